// Round 2
// baseline (3283.503 us; speedup 1.0000x reference)
//
#include <hip/hip_runtime.h>
#include <math.h>

// ---------- helpers: monotone float<->uint for atomicMax on floats ----------
static __device__ __forceinline__ unsigned f2o(float f) {
  unsigned b = __float_as_uint(f);
  return (b & 0x80000000u) ? ~b : (b | 0x80000000u);
}
static __device__ __forceinline__ float o2f(unsigned u) {
  return __uint_as_float((u & 0x80000000u) ? (u & 0x7fffffffu) : ~u);
}

__global__ void zero_u32_kernel(unsigned* __restrict__ p, int n) {
  int i = blockIdx.x * blockDim.x + threadIdx.x;
  if (i < n) p[i] = 0u;
}

// ---------- L2 norms of feature vectors: norm[b,p] = sqrt(sum_c f^2 + 1e-6) ----------
__global__ __launch_bounds__(256) void norms_kernel(const float* __restrict__ fA,
                                                    const float* __restrict__ fB,
                                                    float* __restrict__ nA,
                                                    float* __restrict__ nB) {
  int idx = blockIdx.x * blockDim.x + threadIdx.x;  // 0..8191
  const float* f = (idx & 4096) ? fB : fA;
  float* out = (idx & 4096) ? nB : nA;
  int bp = idx & 4095;
  const float* base = f + ((size_t)(bp >> 10) << 20) + (bp & 1023);
  float s = 0.f;
#pragma unroll 8
  for (int c = 0; c < 1024; ++c) {
    float v = base[(size_t)c << 10];
    s = fmaf(v, v, s);
  }
  out[bp] = sqrtf(s + 1e-6f);
}

// ---------- corr[b,p,q] = dot(fA[b,:,p], fB[b,:,q]) / (nA[b,p]*nB[b,q]) ----------
// A,B are [b][c=1024][pos=1024] (K-major "TN" layout -> coalesced tile loads).
__global__ __launch_bounds__(256) void corr_gemm_kernel(const float* __restrict__ A,
                                                        const float* __restrict__ B,
                                                        const float* __restrict__ nA,
                                                        const float* __restrict__ nB,
                                                        float* __restrict__ C) {
  __shared__ float As[16][64];
  __shared__ float Bs[16][64];
  int b = blockIdx.z;
  int p0 = blockIdx.y << 6, q0 = blockIdx.x << 6;
  const float* Ab = A + ((size_t)b << 20);
  const float* Bb = B + ((size_t)b << 20);
  int tid = threadIdx.x;
  int tx = tid & 15, ty = tid >> 4;
  int lm = tid & 63, lk4 = (tid >> 6) << 2;
  float acc[4][4] = {};
  for (int k0 = 0; k0 < 1024; k0 += 16) {
    __syncthreads();
#pragma unroll
    for (int t = 0; t < 4; ++t) {
      int kk = lk4 + t;
      As[kk][lm] = Ab[((size_t)(k0 + kk) << 10) + p0 + lm];
      Bs[kk][lm] = Bb[((size_t)(k0 + kk) << 10) + q0 + lm];
    }
    __syncthreads();
#pragma unroll
    for (int kk = 0; kk < 16; ++kk) {
      const float4 av = *(const float4*)&As[kk][ty << 2];
      const float4 bv = *(const float4*)&Bs[kk][tx << 2];
      float a4[4] = {av.x, av.y, av.z, av.w};
      float b4[4] = {bv.x, bv.y, bv.z, bv.w};
#pragma unroll
      for (int r = 0; r < 4; ++r)
#pragma unroll
        for (int c = 0; c < 4; ++c) acc[r][c] = fmaf(a4[r], b4[c], acc[r][c]);
    }
  }
  float rn[4], cn[4];
#pragma unroll
  for (int r = 0; r < 4; ++r) rn[r] = nA[(b << 10) + p0 + (ty << 2) + r];
#pragma unroll
  for (int c = 0; c < 4; ++c) cn[c] = nB[(b << 10) + q0 + (tx << 2) + c];
#pragma unroll
  for (int r = 0; r < 4; ++r) {
    float4 o;
    o.x = acc[r][0] / (rn[r] * cn[0]);
    o.y = acc[r][1] / (rn[r] * cn[1]);
    o.z = acc[r][2] / (rn[r] * cn[2]);
    o.w = acc[r][3] / (rn[r] * cn[3]);
    *(float4*)&C[((size_t)b << 20) + ((size_t)(p0 + (ty << 2) + r) << 10) + q0 + (tx << 2)] = o;
  }
}

// ---------- row max: rmax[b*1024+p] = max_q X[b,p,q] ----------
__global__ __launch_bounds__(256) void rowmax_kernel(const float* __restrict__ X,
                                                     float* __restrict__ rmax) {
  int row = blockIdx.x;  // b*1024+p
  const float* x = X + ((size_t)row << 10);
  int tid = threadIdx.x;
  float m = fmaxf(fmaxf(x[tid], x[tid + 256]), fmaxf(x[tid + 512], x[tid + 768]));
  __shared__ float red[256];
  red[tid] = m;
  __syncthreads();
  for (int s = 128; s > 0; s >>= 1) {
    if (tid < s) red[tid] = fmaxf(red[tid], red[tid + s]);
    __syncthreads();
  }
  if (tid == 0) rmax[row] = red[0];
}

// ---------- col max: cmax[b*1024+q] = max_p X[b,p,q] (atomic over p-groups) ----------
__global__ __launch_bounds__(256) void colmax_kernel(const float* __restrict__ X,
                                                     unsigned* __restrict__ cmaxu) {
  // grid: (qgrp=4, pgrp=64, b=4)
  int b = blockIdx.z;
  int q = (blockIdx.x << 8) + threadIdx.x;
  int p0 = blockIdx.y << 4;
  const float* x = X + ((size_t)b << 20) + ((size_t)p0 << 10) + q;
  float m = -INFINITY;
#pragma unroll
  for (int r = 0; r < 16; ++r) m = fmaxf(m, x[(size_t)r << 10]);
  atomicMax(&cmaxu[(b << 10) + q], f2o(m));
}

// ---------- mutual matching elementwise: Y = X^3 / ((rmax+eps)*(cmax+eps)) ----------
__global__ __launch_bounds__(256) void mm_kernel(const float* __restrict__ X,
                                                 const float* __restrict__ rmax,
                                                 const unsigned* __restrict__ cmaxu,
                                                 float* __restrict__ Y) {
  size_t i4 = (size_t)blockIdx.x * 256 + threadIdx.x;  // float4 index, 1M total
  size_t base = i4 << 2;
  float4 x = *(const float4*)&X[base];
  float ma = rmax[base >> 10] + 1e-5f;
  const unsigned* cm = &cmaxu[((base >> 20) << 10) + (base & 1023)];
  float4 y;
  y.x = x.x * x.x * x.x / (ma * (o2f(cm[0]) + 1e-5f));
  y.y = x.y * x.y * x.y / (ma * (o2f(cm[1]) + 1e-5f));
  y.z = x.z * x.z * x.z / (ma * (o2f(cm[2]) + 1e-5f));
  y.w = x.w * x.w * x.w / (ma * (o2f(cm[3]) + 1e-5f));
  *(float4*)&Y[base] = y;
}

// ---------- 4D conv, 3^4 taps, SAME zero pad, + bias + ReLU ----------
// Block = one (b, i, j) output plane (32x32 over k,l), computes ALL CO channels.
// Stages each needed (ci, i+di, j+dj) input plane once into padded LDS, reuses
// across all CO output channels (360 FMA per 18 LDS reads for CO=10).
// SWAP: index weights as W[o,c,dk,dl,di,dj] -> implements P(nc(P(x))) = nc_W'(x).
// ACCUM: += into output (second symmetric branch).
template <int CI, int CO, bool SWAP, bool ACCUM>
__global__ __launch_bounds__(256) void conv4d_kernel(const float* __restrict__ x,
                                                     const float* __restrict__ Wt,
                                                     const float* __restrict__ bias,
                                                     float* __restrict__ y) {
  __shared__ float plane[34][35];  // zero-padded 32x32, +1 col pad for banks
  int ij = blockIdx.x;
  int i = ij >> 5, j = ij & 31;
  int b = blockIdx.y;
  int tid = threadIdx.x;
  int k = tid >> 3;          // 0..31 (output row)
  int l4 = (tid & 7) << 2;   // 0,4,...,28 (output col base, 4 per thread)

  float acc[CO][4];
#pragma unroll
  for (int co = 0; co < CO; ++co) {
    float bv = bias[co];
#pragma unroll
    for (int r = 0; r < 4; ++r) acc[co][r] = bv;
  }

  for (int ci = 0; ci < CI; ++ci) {
    for (int di = -1; di <= 1; ++di) {
      int ii = i + di;
      if (ii < 0 || ii >= 32) continue;  // block-uniform
      for (int dj = -1; dj <= 1; ++dj) {
        int jj = j + dj;
        if (jj < 0 || jj >= 32) continue;  // block-uniform
        const float* src = x + ((size_t)(((b * CI + ci) * 32 + ii) * 32 + jj) << 10);
        __syncthreads();  // prior reads done before overwrite
        for (int idx = tid; idx < 34 * 34; idx += 256) {
          int r = idx / 34, c = idx - r * 34;
          int rr = r - 1, cc = c - 1;
          float v = 0.f;
          if ((unsigned)rr < 32u && (unsigned)cc < 32u) v = src[(rr << 5) + cc];
          plane[r][c] = v;
        }
        __syncthreads();
        float v[3][6];
#pragma unroll
        for (int a = 0; a < 3; ++a)
#pragma unroll
          for (int bb = 0; bb < 6; ++bb) v[a][bb] = plane[k + a][l4 + bb];
        int boff = (di + 1) * 3 + (dj + 1);
#pragma unroll
        for (int co = 0; co < CO; ++co) {
#pragma unroll
          for (int a = 0; a < 3; ++a) {
#pragma unroll
            for (int bc = 0; bc < 3; ++bc) {
              float w = Wt[co * (CI * 81) + ci * 81 +
                           (SWAP ? (a * 3 + bc) * 9 + boff : boff * 9 + (a * 3 + bc))];
#pragma unroll
              for (int r = 0; r < 4; ++r) acc[co][r] = fmaf(v[a][r + bc], w, acc[co][r]);
            }
          }
        }
      }
    }
  }

#pragma unroll
  for (int co = 0; co < CO; ++co) {
    size_t oidx = (((size_t)((b * CO + co) * 1024 + ij)) << 10) + (k << 5) + l4;
    float4 o;
    o.x = fmaxf(acc[co][0], 0.f);
    o.y = fmaxf(acc[co][1], 0.f);
    o.z = fmaxf(acc[co][2], 0.f);
    o.w = fmaxf(acc[co][3], 0.f);
    if (ACCUM) {
      float4 prev = *(const float4*)&y[oidx];
      o.x += prev.x; o.y += prev.y; o.z += prev.z; o.w += prev.w;
    }
    *(float4*)&y[oidx] = o;
  }
}

extern "C" void kernel_launch(void* const* d_in, const int* in_sizes, int n_in,
                              void* d_out, int out_size, void* d_ws, size_t ws_size,
                              hipStream_t stream) {
  const float* fA = (const float*)d_in[0];
  const float* fB = (const float*)d_in[1];
  const float* W1 = (const float*)d_in[2];
  const float* b1 = (const float*)d_in[3];
  const float* W2 = (const float*)d_in[4];
  const float* b2 = (const float*)d_in[5];
  const float* W3 = (const float*)d_in[6];
  const float* b3 = (const float*)d_in[7];
  float* out = (float*)d_out;

  char* ws = (char*)d_ws;
  const size_t SM = 16384;
  float* normA = (float*)(ws + 0 * SM);
  float* normB = (float*)(ws + 1 * SM);
  float* maxA1 = (float*)(ws + 2 * SM);
  float* maxA2 = (float*)(ws + 3 * SM);
  unsigned* maxBu1 = (unsigned*)(ws + 4 * SM);
  unsigned* maxBu2 = (unsigned*)(ws + 5 * SM);
  float* corr = (float*)(ws + 6 * SM);  // 4M floats
  char* tbase = ws + 6 * SM + ((size_t)4 << 20) * sizeof(float);

  // choose batch chunk NB for the 10-channel intermediates
  size_t per_t = (size_t)10 * 1024 * 1024 * sizeof(float);  // 41.9MB per batch
  size_t fixed = 6 * SM + ((size_t)4 << 20) * sizeof(float);
  size_t avail = ws_size > fixed ? ws_size - fixed : 0;
  int NB = 4;
  while (NB > 1 && avail < 2 * per_t * (size_t)NB) NB >>= 1;
  float* t1 = (float*)tbase;
  float* t2 = (float*)(tbase + per_t * (size_t)NB);

  // 1) feature norms
  norms_kernel<<<32, 256, 0, stream>>>(fA, fB, normA, normB);
  // 2) init colmax buffers (both MM passes)
  zero_u32_kernel<<<32, 256, 0, stream>>>(maxBu1, 8192);
  // 3) correlation GEMM (normalized via epilogue scaling)
  corr_gemm_kernel<<<dim3(16, 16, 4), 256, 0, stream>>>(fA, fB, normA, normB, corr);
  // 4) mutual matching #1
  rowmax_kernel<<<4096, 256, 0, stream>>>(corr, maxA1);
  colmax_kernel<<<dim3(4, 64, 4), 256, 0, stream>>>(corr, maxBu1);
  mm_kernel<<<4096, 256, 0, stream>>>(corr, maxA1, maxBu1, corr);
  // 5) symmetric neighbourhood-consensus stacks; d_out is the accumulator
  for (int b0 = 0; b0 < 4; b0 += NB) {
    dim3 g(1024, NB);
    const float* cin = corr + ((size_t)b0 << 20);
    float* symo = out + ((size_t)b0 << 20);
    conv4d_kernel<1, 10, false, false><<<g, 256, 0, stream>>>(cin, W1, b1, t1);
    conv4d_kernel<10, 10, false, false><<<g, 256, 0, stream>>>(t1, W2, b2, t2);
    conv4d_kernel<10, 1, false, false><<<g, 256, 0, stream>>>(t2, W3, b3, symo);
    conv4d_kernel<1, 10, true, false><<<g, 256, 0, stream>>>(cin, W1, b1, t1);
    conv4d_kernel<10, 10, true, false><<<g, 256, 0, stream>>>(t1, W2, b2, t2);
    conv4d_kernel<10, 1, true, true><<<g, 256, 0, stream>>>(t2, W3, b3, symo);
  }
  // 6) mutual matching #2 (in place on d_out)
  rowmax_kernel<<<4096, 256, 0, stream>>>(out, maxA2);
  colmax_kernel<<<dim3(4, 64, 4), 256, 0, stream>>>(out, maxBu2);
  mm_kernel<<<4096, 256, 0, stream>>>(out, maxA2, maxBu2, out);
}

// Round 3
// 2514.621 us; speedup vs baseline: 1.3058x; 1.3058x over previous
//
#include <hip/hip_runtime.h>
#include <math.h>

typedef _Float16 half8 __attribute__((ext_vector_type(8)));
typedef _Float16 half2t __attribute__((ext_vector_type(2)));
typedef float floatx4 __attribute__((ext_vector_type(4)));

static __device__ __forceinline__ unsigned f2o(float f) {
  unsigned b = __float_as_uint(f);
  return (b & 0x80000000u) ? ~b : (b | 0x80000000u);
}
static __device__ __forceinline__ float o2f(unsigned u) {
  return __uint_as_float((u & 0x80000000u) ? (u & 0x7fffffffu) : ~u);
}
static __device__ __forceinline__ unsigned pack2(float a, float b) {
  _Float16 ha = (_Float16)a, hb = (_Float16)b;
  unsigned short ua = __builtin_bit_cast(unsigned short, ha);
  unsigned short ub = __builtin_bit_cast(unsigned short, hb);
  return (unsigned)ua | ((unsigned)ub << 16);
}
static __device__ __forceinline__ float dot2acc(unsigned x, unsigned w, float acc) {
  half2t xh = __builtin_bit_cast(half2t, x);
  half2t wh = __builtin_bit_cast(half2t, w);
#if __has_builtin(__builtin_amdgcn_fdot2)
  return __builtin_amdgcn_fdot2(xh, wh, acc, false);
#else
  return fmaf((float)xh[0], (float)wh[0], fmaf((float)xh[1], (float)wh[1], acc));
#endif
}

__global__ void nc_zero_u32(unsigned* __restrict__ p, int n) {
  int i = blockIdx.x * blockDim.x + threadIdx.x;
  if (i < n) p[i] = 0u;
}

// ---------- L2 norms (fp32, unchanged) ----------
__global__ __launch_bounds__(256) void nc_norms(const float* __restrict__ fA,
                                                const float* __restrict__ fB,
                                                float* __restrict__ nA,
                                                float* __restrict__ nB) {
  int idx = blockIdx.x * blockDim.x + threadIdx.x;
  const float* f = (idx & 4096) ? fB : fA;
  float* out = (idx & 4096) ? nB : nA;
  int bp = idx & 4095;
  const float* base = f + ((size_t)(bp >> 10) << 20) + (bp & 1023);
  float s = 0.f;
#pragma unroll 8
  for (int c = 0; c < 1024; ++c) {
    float v = base[(size_t)c << 10];
    s = fmaf(v, v, s);
  }
  out[bp] = sqrtf(s + 1e-6f);
}

// ---------- correlation GEMM (fp32, unchanged) ----------
__global__ __launch_bounds__(256) void nc_gemm(const float* __restrict__ A,
                                               const float* __restrict__ B,
                                               const float* __restrict__ nA,
                                               const float* __restrict__ nB,
                                               float* __restrict__ C) {
  __shared__ float As[16][64];
  __shared__ float Bs[16][64];
  int b = blockIdx.z;
  int p0 = blockIdx.y << 6, q0 = blockIdx.x << 6;
  const float* Ab = A + ((size_t)b << 20);
  const float* Bb = B + ((size_t)b << 20);
  int tid = threadIdx.x;
  int tx = tid & 15, ty = tid >> 4;
  int lm = tid & 63, lk4 = (tid >> 6) << 2;
  float acc[4][4] = {};
  for (int k0 = 0; k0 < 1024; k0 += 16) {
    __syncthreads();
#pragma unroll
    for (int t = 0; t < 4; ++t) {
      int kk = lk4 + t;
      As[kk][lm] = Ab[((size_t)(k0 + kk) << 10) + p0 + lm];
      Bs[kk][lm] = Bb[((size_t)(k0 + kk) << 10) + q0 + lm];
    }
    __syncthreads();
#pragma unroll
    for (int kk = 0; kk < 16; ++kk) {
      const float4 av = *(const float4*)&As[kk][ty << 2];
      const float4 bv = *(const float4*)&Bs[kk][tx << 2];
      float a4[4] = {av.x, av.y, av.z, av.w};
      float b4[4] = {bv.x, bv.y, bv.z, bv.w};
#pragma unroll
      for (int r = 0; r < 4; ++r)
#pragma unroll
        for (int c = 0; c < 4; ++c) acc[r][c] = fmaf(a4[r], b4[c], acc[r][c]);
    }
  }
  float rn[4], cn[4];
#pragma unroll
  for (int r = 0; r < 4; ++r) rn[r] = nA[(b << 10) + p0 + (ty << 2) + r];
#pragma unroll
  for (int c = 0; c < 4; ++c) cn[c] = nB[(b << 10) + q0 + (tx << 2) + c];
#pragma unroll
  for (int r = 0; r < 4; ++r) {
    float4 o;
    o.x = acc[r][0] / (rn[r] * cn[0]);
    o.y = acc[r][1] / (rn[r] * cn[1]);
    o.z = acc[r][2] / (rn[r] * cn[2]);
    o.w = acc[r][3] / (rn[r] * cn[3]);
    *(float4*)&C[((size_t)b << 20) + ((size_t)(p0 + (ty << 2) + r) << 10) + q0 + (tx << 2)] = o;
  }
}

// ---------- row / col max (fp32, unchanged) ----------
__global__ __launch_bounds__(256) void nc_rowmax(const float* __restrict__ X,
                                                 float* __restrict__ rmax) {
  int row = blockIdx.x;
  const float* x = X + ((size_t)row << 10);
  int tid = threadIdx.x;
  float m = fmaxf(fmaxf(x[tid], x[tid + 256]), fmaxf(x[tid + 512], x[tid + 768]));
  __shared__ float red[256];
  red[tid] = m;
  __syncthreads();
  for (int s = 128; s > 0; s >>= 1) {
    if (tid < s) red[tid] = fmaxf(red[tid], red[tid + s]);
    __syncthreads();
  }
  if (tid == 0) rmax[row] = red[0];
}

__global__ __launch_bounds__(256) void nc_colmax(const float* __restrict__ X,
                                                 unsigned* __restrict__ cmaxu) {
  int b = blockIdx.z;
  int q = (blockIdx.x << 8) + threadIdx.x;
  int p0 = blockIdx.y << 4;
  const float* x = X + ((size_t)b << 20) + ((size_t)p0 << 10) + q;
  float m = -INFINITY;
#pragma unroll
  for (int r = 0; r < 16; ++r) m = fmaxf(m, x[(size_t)r << 10]);
  atomicMax(&cmaxu[(b << 10) + q], f2o(m));
}

// ---------- mutual matching: fp32 out (final) ----------
__global__ __launch_bounds__(256) void nc_mm_f32(const float* __restrict__ X,
                                                 const float* __restrict__ rmax,
                                                 const unsigned* __restrict__ cmaxu,
                                                 float* __restrict__ Y) {
  size_t i4 = (size_t)blockIdx.x * 256 + threadIdx.x;
  size_t base = i4 << 2;
  float4 x = *(const float4*)&X[base];
  float ma = rmax[base >> 10] + 1e-5f;
  const unsigned* cm = &cmaxu[((base >> 20) << 10) + (base & 1023)];
  float4 y;
  y.x = x.x * x.x * x.x / (ma * (o2f(cm[0]) + 1e-5f));
  y.y = x.y * x.y * x.y / (ma * (o2f(cm[1]) + 1e-5f));
  y.z = x.z * x.z * x.z / (ma * (o2f(cm[2]) + 1e-5f));
  y.w = x.w * x.w * x.w / (ma * (o2f(cm[3]) + 1e-5f));
  *(float4*)&Y[base] = y;
}

// ---------- mutual matching: f16 out (feeds conv stack) ----------
__global__ __launch_bounds__(256) void nc_mm_f16(const float* __restrict__ X,
                                                 const float* __restrict__ rmax,
                                                 const unsigned* __restrict__ cmaxu,
                                                 unsigned short* __restrict__ Y16) {
  size_t i4 = (size_t)blockIdx.x * 256 + threadIdx.x;
  size_t base = i4 << 2;
  float4 x = *(const float4*)&X[base];
  float ma = rmax[base >> 10] + 1e-5f;
  const unsigned* cm = &cmaxu[((base >> 20) << 10) + (base & 1023)];
  float y0 = x.x * x.x * x.x / (ma * (o2f(cm[0]) + 1e-5f));
  float y1 = x.y * x.y * x.y / (ma * (o2f(cm[1]) + 1e-5f));
  float y2 = x.z * x.z * x.z / (ma * (o2f(cm[2]) + 1e-5f));
  float y3 = x.w * x.w * x.w / (ma * (o2f(cm[3]) + 1e-5f));
  unsigned* dst = (unsigned*)&Y16[base];
  dst[0] = pack2(y0, y1);
  dst[1] = pack2(y2, y3);
}

// ---------- weight prepack ----------
// Wf frags (512 f16 each, MFMA A layout: elem e=lane*8+j -> A[co=lane&15][k=(lane>>4)*8+j]):
//   frag 0..8    conv1 variant0 taps ; 9..17  conv1 variant1
//   frag 18..44  conv2 variant0 (chunk*9+tap) ; 45..71 conv2 variant1
// w3p: [v][pair(5)][r9(di,dj)*9 + ab] packed half2 over ci pairs
__global__ void nc_wpack(const float* __restrict__ W1, const float* __restrict__ W2,
                         const float* __restrict__ W3,
                         unsigned short* __restrict__ Wf, unsigned* __restrict__ w3p) {
  int f = blockIdx.x;
  int t = threadIdx.x;
  if (f < 72) {
    int v, chunk, tap, CI;
    const float* W;
    if (f < 18) { v = f / 9; tap = f % 9; chunk = 0; CI = 1; W = W1; }
    else { int g = f - 18; v = g / 27; g %= 27; chunk = g / 9; tap = g % 9; CI = 10; W = W2; }
    for (int e = t; e < 512; e += 256) {
      int lane = e >> 3, j = e & 7;
      int co = lane & 15;
      int k = ((lane >> 4) << 3) + j;
      int cip = chunk * 32 + k;
      float val = 0.f;
      if (co < 10 && cip < CI * 9) {
        int ci = cip / 9, r = cip % 9;
        int widx = v ? (tap * 9 + r) : (r * 9 + tap);
        val = W[(co * CI + ci) * 81 + widx];
      }
      _Float16 h = (_Float16)val;
      Wf[f * 512 + e] = __builtin_bit_cast(unsigned short, h);
    }
  } else {
    for (int e = t; e < 2 * 5 * 81; e += 256) {
      int v = e / 405;
      int rem = e - v * 405;
      int p = rem / 81;
      int t81 = rem - p * 81;
      int r = t81 / 9, ab = t81 - r * 9;
      int widx = v ? (ab * 9 + r) : (r * 9 + ab);
      w3p[e] = pack2(W3[(2 * p) * 81 + widx], W3[(2 * p + 1) * 81 + widx]);
    }
  }
}

// ---------- MFMA 4D conv (conv1: CI=1,OUTMODE=0 ; conv2: CI=10,OUTMODE=1) ----------
// y[co, n] += sum_{ci'=(ci,di,dj)} W[co,ci',tap] * x[ci', n+shift(tap)] over 9 taps (dk,dl)
// Block: one (b, i, j) output plane. LDS: xs[pos=576(src rows 16h-1..16h+16)][kstride=36] f16 + 64B zero slot.
template <int CI, int OUTMODE>
__global__ __launch_bounds__(256) void nc_conv_mfma(
    const unsigned short* __restrict__ xin, const unsigned short* __restrict__ Wf,
    const float* __restrict__ bias, void* __restrict__ yout) {
  constexpr int NCH = (CI * 9 + 31) / 32;
  __shared__ unsigned short xs[576 * 36 + 32];
  const int ZBYTE = 576 * 72;  // zero-slot byte offset
  int ij = blockIdx.x, b = blockIdx.y;
  int i = ij >> 5, j = ij & 31;
  int tid = threadIdx.x;
  int lane = tid & 63, w = tid >> 6;
  int ncol = lane & 15, g4 = lane >> 4;

  if (tid < 16) ((unsigned*)((char*)xs + ZBYTE))[tid] = 0u;

  // staging assignment
  int kp = tid >> 4;          // k-pair 0..15
  int lp0 = (tid & 15) << 2;  // pos base

  // per-lane output coords per q-group
  int ko[8], lo[8], lpb[8];
#pragma unroll
  for (int q = 0; q < 8; ++q) {
    int nl = (((w << 3) + q) << 4) | ncol;  // [0,512)
    lpb[q] = nl + 32;
    lo[q] = nl & 31;
    ko[q] = nl >> 5;  // local row; global = h*16 + ko
  }

  for (int h = 0; h < 2; ++h) {
    floatx4 acc[8];
#pragma unroll
    for (int q = 0; q < 8; ++q) acc[q] = (floatx4){0.f, 0.f, 0.f, 0.f};

    for (int ch = 0; ch < NCH; ++ch) {
      __syncthreads();
      // ---- stage chunk ch (32 k-values as 16 pairs), half h ----
      {
        int k0 = ch * 32 + (kp << 1);
        const unsigned short* pl0 = nullptr;
        const unsigned short* pl1 = nullptr;
        {
          int cip = k0;
          if (cip < CI * 9) {
            int ci = cip / 9, r = cip % 9;
            int ii = i + r / 3 - 1, jj = j + (r % 3) - 1;
            if ((unsigned)ii < 32u && (unsigned)jj < 32u)
              pl0 = xin + ((size_t)(b * CI + ci) * 1024 + ii * 32 + jj) * 1024;
          }
          cip = k0 + 1;
          if (cip < CI * 9) {
            int ci = cip / 9, r = cip % 9;
            int ii = i + r / 3 - 1, jj = j + (r % 3) - 1;
            if ((unsigned)ii < 32u && (unsigned)jj < 32u)
              pl1 = xin + ((size_t)(b * CI + ci) * 1024 + ii * 32 + jj) * 1024;
          }
        }
        unsigned* dst = (unsigned*)xs;
#pragma unroll
        for (int s = 0; s < 9; ++s) {
          int lp = lp0 + (s << 6);
          int row = (h << 4) - 1 + (lp >> 5);
          int col = lp & 31;
          bool rv = (unsigned)row < 32u;
          ushort4 a0 = {0, 0, 0, 0}, a1 = {0, 0, 0, 0};
          if (rv && pl0) a0 = *(const ushort4*)(pl0 + (row << 5) + col);
          if (rv && pl1) a1 = *(const ushort4*)(pl1 + (row << 5) + col);
          dst[(lp + 0) * 18 + kp] = (unsigned)a0.x | ((unsigned)a1.x << 16);
          dst[(lp + 1) * 18 + kp] = (unsigned)a0.y | ((unsigned)a1.y << 16);
          dst[(lp + 2) * 18 + kp] = (unsigned)a0.z | ((unsigned)a1.z << 16);
          dst[(lp + 3) * 18 + kp] = (unsigned)a0.w | ((unsigned)a1.w << 16);
        }
      }
      __syncthreads();

      // ---- A fragments for this chunk (9 taps) ----
      half8 afr[9];
      const unsigned short* wfp = Wf + (ch * 9) * 512 + (lane << 3);
#pragma unroll
      for (int t9 = 0; t9 < 9; ++t9) afr[t9] = *(const half8*)(wfp + t9 * 512);

      // ---- 9 shifted MFMA accumulations ----
#pragma unroll
      for (int dk = -1; dk <= 1; ++dk) {
#pragma unroll
        for (int dl = -1; dl <= 1; ++dl) {
          int tap = (dk + 1) * 3 + (dl + 1);
          half8 af = afr[tap];
          int shift = dk * 32 + dl;
#pragma unroll
          for (int q = 0; q < 8; ++q) {
            bool valid = ((unsigned)(ko[q] + (h << 4) + dk) < 32u) &
                         ((unsigned)(lo[q] + dl) < 32u);
            int lp = lpb[q] + shift;
            int byteoff = valid ? (lp * 72 + (g4 << 4)) : (ZBYTE + (g4 << 4));
            const char* src = (const char*)xs + byteoff;
            union { unsigned long long u[2]; half8 v; } bb;
            bb.u[0] = *(const unsigned long long*)(src);
            bb.u[1] = *(const unsigned long long*)(src + 8);
            acc[q] = __builtin_amdgcn_mfma_f32_16x16x32_f16(af, bb.v, acc[q], 0, 0, 0);
          }
        }
      }
    }

    // ---- epilogue for half h ----
#pragma unroll
    for (int q = 0; q < 8; ++q) {
      int ng = (h << 9) + ((((w << 3) + q) << 4) | ncol);
      if (OUTMODE == 0) {
        unsigned short* t1 = (unsigned short*)yout;
#pragma unroll
        for (int r = 0; r < 4; ++r) {
          int co = (g4 << 2) + r;
          if (co < 10) {
            float vv = fmaxf(acc[q][r] + bias[co], 0.f);
            _Float16 hh = (_Float16)vv;
            t1[((size_t)(b * 10 + co) * 1024 + ij) * 1024 + ng] =
                __builtin_bit_cast(unsigned short, hh);
          }
        }
      } else {
        unsigned* t2p = (unsigned*)yout;
        int c0 = g4 << 2;
        float v0 = fmaxf(acc[q][0] + (c0 + 0 < 10 ? bias[c0 + 0] : 0.f), 0.f);
        float v1 = fmaxf(acc[q][1] + (c0 + 1 < 10 ? bias[c0 + 1] : 0.f), 0.f);
        float v2 = fmaxf(acc[q][2] + (c0 + 2 < 10 ? bias[c0 + 2] : 0.f), 0.f);
        float v3 = fmaxf(acc[q][3] + (c0 + 3 < 10 ? bias[c0 + 3] : 0.f), 0.f);
        int p0 = g4 << 1;
        if (p0 < 5)
          t2p[((size_t)(b * 5 + p0) * 1024 + ij) * 1024 + ng] = pack2(v0, v1);
        if (p0 + 1 < 5)
          t2p[((size_t)(b * 5 + p0 + 1) * 1024 + ij) * 1024 + ng] = pack2(v2, v3);
      }
    }
  }
}

// ---------- conv3 (10 -> 1) via v_dot2 over ci-pairs ----------
template <bool ACCUM>
__global__ __launch_bounds__(256) void nc_conv3(
    const unsigned* __restrict__ t2p, const unsigned* __restrict__ w3p,
    const float* __restrict__ b3, float* __restrict__ yout) {
  __shared__ unsigned xs2[5][33 * 32];
  int ij = blockIdx.x, b = blockIdx.y;
  int i = ij >> 5, j = ij & 31;
  int tid = threadIdx.x;
  int k = tid >> 3, l4 = (tid & 7) << 2;
  float acc[4] = {0.f, 0.f, 0.f, 0.f};

  for (int di = -1; di <= 1; ++di) {
    int ii = i + di;
    for (int dj = -1; dj <= 1; ++dj) {
      int jj = j + dj;
      bool pv = ((unsigned)ii < 32u) && ((unsigned)jj < 32u);
      if (!pv) continue;  // block-uniform
      __syncthreads();
#pragma unroll
      for (int p = 0; p < 5; ++p) {
#pragma unroll
        for (int s = 0; s < 4; ++s) {
          int pos = (s << 8) + tid;
          unsigned v = t2p[((size_t)(b * 5 + p) * 1024 + ii * 32 + jj) * 1024 + pos];
          xs2[p][(pos >> 5) * 33 + (pos & 31)] = v;
        }
      }
      __syncthreads();
      int r9 = (di + 1) * 3 + (dj + 1);
#pragma unroll
      for (int p = 0; p < 5; ++p) {
        unsigned vv[3][6];
#pragma unroll
        for (int a = 0; a < 3; ++a)
#pragma unroll
          for (int bb2 = 0; bb2 < 6; ++bb2) {
            int rr = k + a - 1, cc = l4 + bb2 - 1;
            unsigned x = 0;
            if ((unsigned)rr < 32u && (unsigned)cc < 32u) x = xs2[p][rr * 33 + cc];
            vv[a][bb2] = x;
          }
#pragma unroll
        for (int a = 0; a < 3; ++a)
#pragma unroll
          for (int bc = 0; bc < 3; ++bc) {
            unsigned wp = w3p[p * 81 + r9 * 9 + a * 3 + bc];
#pragma unroll
            for (int r = 0; r < 4; ++r) acc[r] = dot2acc(vv[a][r + bc], wp, acc[r]);
          }
      }
    }
  }
  float bb = b3[0];
  size_t o = ((size_t)b * 1024 + ij) * 1024 + (k << 5) + l4;
  float4 out4;
  out4.x = fmaxf(acc[0] + bb, 0.f);
  out4.y = fmaxf(acc[1] + bb, 0.f);
  out4.z = fmaxf(acc[2] + bb, 0.f);
  out4.w = fmaxf(acc[3] + bb, 0.f);
  if (ACCUM) {
    float4 prev = *(const float4*)&yout[o];
    out4.x += prev.x; out4.y += prev.y; out4.z += prev.z; out4.w += prev.w;
  }
  *(float4*)&yout[o] = out4;
}

extern "C" void kernel_launch(void* const* d_in, const int* in_sizes, int n_in,
                              void* d_out, int out_size, void* d_ws, size_t ws_size,
                              hipStream_t stream) {
  const float* fA = (const float*)d_in[0];
  const float* fB = (const float*)d_in[1];
  const float* W1 = (const float*)d_in[2];
  const float* b1 = (const float*)d_in[3];
  const float* W2 = (const float*)d_in[4];
  const float* b2 = (const float*)d_in[5];
  const float* W3 = (const float*)d_in[6];
  const float* b3 = (const float*)d_in[7];
  float* out = (float*)d_out;

  char* ws = (char*)d_ws;
  const size_t SM = 16384;
  float* normA = (float*)(ws + 0 * SM);
  float* normB = (float*)(ws + 1 * SM);
  float* maxA1 = (float*)(ws + 2 * SM);
  float* maxA2 = (float*)(ws + 3 * SM);
  unsigned* maxBu1 = (unsigned*)(ws + 4 * SM);  // zeroed together with maxBu2
  unsigned* maxBu2 = (unsigned*)(ws + 5 * SM);
  char* p = ws + 6 * SM;
  float* corr = (float*)p;              p += (size_t)4 * 1024 * 1024 * 4;   // 16.78 MB
  unsigned short* mm1h = (unsigned short*)p; p += (size_t)4 * 1024 * 1024 * 2;  // 8.39 MB
  unsigned short* t1 = (unsigned short*)p;   p += (size_t)40 * 1024 * 1024 * 2; // 83.9 MB
  unsigned* t2p = (unsigned*)p;         p += (size_t)20 * 1024 * 1024 * 4;  // 83.9 MB
  unsigned short* Wf = (unsigned short*)p;   p += 72 * 512 * 2;             // 73.7 KB
  unsigned* w3p = (unsigned*)p;

  // front-end (fp32, unchanged numerics)
  nc_norms<<<32, 256, 0, stream>>>(fA, fB, normA, normB);
  nc_zero_u32<<<32, 256, 0, stream>>>(maxBu1, 8192);  // covers maxBu1+maxBu2
  nc_wpack<<<73, 256, 0, stream>>>(W1, W2, W3, Wf, w3p);
  nc_gemm<<<dim3(16, 16, 4), 256, 0, stream>>>(fA, fB, normA, normB, corr);
  nc_rowmax<<<4096, 256, 0, stream>>>(corr, maxA1);
  nc_colmax<<<dim3(4, 64, 4), 256, 0, stream>>>(corr, maxBu1);
  nc_mm_f16<<<4096, 256, 0, stream>>>(corr, maxA1, maxBu1, mm1h);

  dim3 cg(1024, 4);
  // branch A (normal weights)
  nc_conv_mfma<1, 0><<<cg, 256, 0, stream>>>(mm1h, Wf + 0 * 512, b1, t1);
  nc_conv_mfma<10, 1><<<cg, 256, 0, stream>>>(t1, Wf + 18 * 512, b2, t2p);
  nc_conv3<false><<<cg, 256, 0, stream>>>(t2p, w3p + 0, b3, out);
  // branch B (axis-swapped weights == P . nc . P)
  nc_conv_mfma<1, 0><<<cg, 256, 0, stream>>>(mm1h, Wf + 9 * 512, b1, t1);
  nc_conv_mfma<10, 1><<<cg, 256, 0, stream>>>(t1, Wf + 45 * 512, b2, t2p);
  nc_conv3<true><<<cg, 256, 0, stream>>>(t2p, w3p + 405, b3, out);

  // final mutual matching (fp32, in place on d_out)
  nc_rowmax<<<4096, 256, 0, stream>>>(out, maxA2);
  nc_colmax<<<dim3(4, 64, 4), 256, 0, stream>>>(out, maxBu2);
  nc_mm_f32<<<4096, 256, 0, stream>>>(out, maxA2, maxBu2, out);
}

// Round 4
// 1231.837 us; speedup vs baseline: 2.6655x; 2.0414x over previous
//
#include <hip/hip_runtime.h>
#include <math.h>

typedef _Float16 half8 __attribute__((ext_vector_type(8)));
typedef _Float16 half2t __attribute__((ext_vector_type(2)));
typedef float floatx4 __attribute__((ext_vector_type(4)));

static __device__ __forceinline__ unsigned f2o(float f) {
  unsigned b = __float_as_uint(f);
  return (b & 0x80000000u) ? ~b : (b | 0x80000000u);
}
static __device__ __forceinline__ float o2f(unsigned u) {
  return __uint_as_float((u & 0x80000000u) ? (u & 0x7fffffffu) : ~u);
}
static __device__ __forceinline__ unsigned pack2(float a, float b) {
  _Float16 ha = (_Float16)a, hb = (_Float16)b;
  unsigned short ua = __builtin_bit_cast(unsigned short, ha);
  unsigned short ub = __builtin_bit_cast(unsigned short, hb);
  return (unsigned)ua | ((unsigned)ub << 16);
}
static __device__ __forceinline__ float dot2acc(unsigned x, unsigned w, float acc) {
  half2t xh = __builtin_bit_cast(half2t, x);
  half2t wh = __builtin_bit_cast(half2t, w);
#if __has_builtin(__builtin_amdgcn_fdot2)
  return __builtin_amdgcn_fdot2(xh, wh, acc, false);
#else
  return fmaf((float)xh[0], (float)wh[0], fmaf((float)xh[1], (float)wh[1], acc));
#endif
}

__global__ void nc_zero_u32(unsigned* __restrict__ p, int n) {
  int i = blockIdx.x * blockDim.x + threadIdx.x;
  if (i < n) p[i] = 0u;
}

// ---------- L2 norms (fp32) ----------
__global__ __launch_bounds__(256) void nc_norms(const float* __restrict__ fA,
                                                const float* __restrict__ fB,
                                                float* __restrict__ nA,
                                                float* __restrict__ nB) {
  int idx = blockIdx.x * blockDim.x + threadIdx.x;
  const float* f = (idx & 4096) ? fB : fA;
  float* out = (idx & 4096) ? nB : nA;
  int bp = idx & 4095;
  const float* base = f + ((size_t)(bp >> 10) << 20) + (bp & 1023);
  float s = 0.f;
#pragma unroll 8
  for (int c = 0; c < 1024; ++c) {
    float v = base[(size_t)c << 10];
    s = fmaf(v, v, s);
  }
  out[bp] = sqrtf(s + 1e-6f);
}

// ---------- correlation GEMM (fp32) ----------
__global__ __launch_bounds__(256) void nc_gemm(const float* __restrict__ A,
                                               const float* __restrict__ B,
                                               const float* __restrict__ nA,
                                               const float* __restrict__ nB,
                                               float* __restrict__ C) {
  __shared__ float As[16][64];
  __shared__ float Bs[16][64];
  int b = blockIdx.z;
  int p0 = blockIdx.y << 6, q0 = blockIdx.x << 6;
  const float* Ab = A + ((size_t)b << 20);
  const float* Bb = B + ((size_t)b << 20);
  int tid = threadIdx.x;
  int tx = tid & 15, ty = tid >> 4;
  int lm = tid & 63, lk4 = (tid >> 6) << 2;
  float acc[4][4] = {};
  for (int k0 = 0; k0 < 1024; k0 += 16) {
    __syncthreads();
#pragma unroll
    for (int t = 0; t < 4; ++t) {
      int kk = lk4 + t;
      As[kk][lm] = Ab[((size_t)(k0 + kk) << 10) + p0 + lm];
      Bs[kk][lm] = Bb[((size_t)(k0 + kk) << 10) + q0 + lm];
    }
    __syncthreads();
#pragma unroll
    for (int kk = 0; kk < 16; ++kk) {
      const float4 av = *(const float4*)&As[kk][ty << 2];
      const float4 bv = *(const float4*)&Bs[kk][tx << 2];
      float a4[4] = {av.x, av.y, av.z, av.w};
      float b4[4] = {bv.x, bv.y, bv.z, bv.w};
#pragma unroll
      for (int r = 0; r < 4; ++r)
#pragma unroll
        for (int c = 0; c < 4; ++c) acc[r][c] = fmaf(a4[r], b4[c], acc[r][c]);
    }
  }
  float rn[4], cn[4];
#pragma unroll
  for (int r = 0; r < 4; ++r) rn[r] = nA[(b << 10) + p0 + (ty << 2) + r];
#pragma unroll
  for (int c = 0; c < 4; ++c) cn[c] = nB[(b << 10) + q0 + (tx << 2) + c];
#pragma unroll
  for (int r = 0; r < 4; ++r) {
    float4 o;
    o.x = acc[r][0] / (rn[r] * cn[0]);
    o.y = acc[r][1] / (rn[r] * cn[1]);
    o.z = acc[r][2] / (rn[r] * cn[2]);
    o.w = acc[r][3] / (rn[r] * cn[3]);
    *(float4*)&C[((size_t)b << 20) + ((size_t)(p0 + (ty << 2) + r) << 10) + q0 + (tx << 2)] = o;
  }
}

// ---------- row / col max (fp32) ----------
__global__ __launch_bounds__(256) void nc_rowmax(const float* __restrict__ X,
                                                 float* __restrict__ rmax) {
  int row = blockIdx.x;
  const float* x = X + ((size_t)row << 10);
  int tid = threadIdx.x;
  float m = fmaxf(fmaxf(x[tid], x[tid + 256]), fmaxf(x[tid + 512], x[tid + 768]));
  __shared__ float red[256];
  red[tid] = m;
  __syncthreads();
  for (int s = 128; s > 0; s >>= 1) {
    if (tid < s) red[tid] = fmaxf(red[tid], red[tid + s]);
    __syncthreads();
  }
  if (tid == 0) rmax[row] = red[0];
}

__global__ __launch_bounds__(256) void nc_colmax(const float* __restrict__ X,
                                                 unsigned* __restrict__ cmaxu) {
  int b = blockIdx.z;
  int q = (blockIdx.x << 8) + threadIdx.x;
  int p0 = blockIdx.y << 4;
  const float* x = X + ((size_t)b << 20) + ((size_t)p0 << 10) + q;
  float m = -INFINITY;
#pragma unroll
  for (int r = 0; r < 16; ++r) m = fmaxf(m, x[(size_t)r << 10]);
  atomicMax(&cmaxu[(b << 10) + q], f2o(m));
}

// ---------- mutual matching ----------
__global__ __launch_bounds__(256) void nc_mm_f32(const float* __restrict__ X,
                                                 const float* __restrict__ rmax,
                                                 const unsigned* __restrict__ cmaxu,
                                                 float* __restrict__ Y) {
  size_t i4 = (size_t)blockIdx.x * 256 + threadIdx.x;
  size_t base = i4 << 2;
  float4 x = *(const float4*)&X[base];
  float ma = rmax[base >> 10] + 1e-5f;
  const unsigned* cm = &cmaxu[((base >> 20) << 10) + (base & 1023)];
  float4 y;
  y.x = x.x * x.x * x.x / (ma * (o2f(cm[0]) + 1e-5f));
  y.y = x.y * x.y * x.y / (ma * (o2f(cm[1]) + 1e-5f));
  y.z = x.z * x.z * x.z / (ma * (o2f(cm[2]) + 1e-5f));
  y.w = x.w * x.w * x.w / (ma * (o2f(cm[3]) + 1e-5f));
  *(float4*)&Y[base] = y;
}

__global__ __launch_bounds__(256) void nc_mm_f16(const float* __restrict__ X,
                                                 const float* __restrict__ rmax,
                                                 const unsigned* __restrict__ cmaxu,
                                                 unsigned short* __restrict__ Y16) {
  size_t i4 = (size_t)blockIdx.x * 256 + threadIdx.x;
  size_t base = i4 << 2;
  float4 x = *(const float4*)&X[base];
  float ma = rmax[base >> 10] + 1e-5f;
  const unsigned* cm = &cmaxu[((base >> 20) << 10) + (base & 1023)];
  float y0 = x.x * x.x * x.x / (ma * (o2f(cm[0]) + 1e-5f));
  float y1 = x.y * x.y * x.y / (ma * (o2f(cm[1]) + 1e-5f));
  float y2 = x.z * x.z * x.z / (ma * (o2f(cm[2]) + 1e-5f));
  float y3 = x.w * x.w * x.w / (ma * (o2f(cm[3]) + 1e-5f));
  unsigned* dst = (unsigned*)&Y16[base];
  dst[0] = pack2(y0, y1);
  dst[1] = pack2(y2, y3);
}

// ---------- weight prepack (unchanged layout) ----------
__global__ void nc_wpack(const float* __restrict__ W1, const float* __restrict__ W2,
                         const float* __restrict__ W3,
                         unsigned short* __restrict__ Wf, unsigned* __restrict__ w3p) {
  int f = blockIdx.x;
  int t = threadIdx.x;
  if (f < 72) {
    int v, chunk, tap, CI;
    const float* W;
    if (f < 18) { v = f / 9; tap = f % 9; chunk = 0; CI = 1; W = W1; }
    else { int g = f - 18; v = g / 27; g %= 27; chunk = g / 9; tap = g % 9; CI = 10; W = W2; }
    for (int e = t; e < 512; e += 256) {
      int lane = e >> 3, j = e & 7;
      int co = lane & 15;
      int k = ((lane >> 4) << 3) + j;
      int cip = chunk * 32 + k;
      float val = 0.f;
      if (co < 10 && cip < CI * 9) {
        int ci = cip / 9, r = cip % 9;
        int widx = v ? (tap * 9 + r) : (r * 9 + tap);
        val = W[(co * CI + ci) * 81 + widx];
      }
      _Float16 h = (_Float16)val;
      Wf[f * 512 + e] = __builtin_bit_cast(unsigned short, h);
    }
  } else {
    for (int e = t; e < 2 * 5 * 81; e += 256) {
      int v = e / 405;
      int rem = e - v * 405;
      int p = rem / 81;
      int t81 = rem - p * 81;
      int r = t81 / 9, ab = t81 - r * 9;
      int widx = v ? (ab * 9 + r) : (r * 9 + ab);
      w3p[e] = pack2(W3[(2 * p) * 81 + widx], W3[(2 * p + 1) * 81 + widx]);
    }
  }
}

// ---------- MFMA 4D conv, quarter-plane blocks ----------
// Block = (ij, quarter, b): 8 output k-rows (256 pos), all CO.
// LDS layout: xs[pos][kslot], pos = row*36 + 1 + l (row 0..9 = global k rows
// qt*8-1 .. qt*8+8; l-halo cols 0,33 zeroed), kslot stride 40 halves (pad 32->40
// => stride 20 words: conflict-free b128 reads). All boundary zeros are
// materialized in LDS, so tap reads are ds_read_b128 base+const-offset, no masks.
template <int CI, int OUTMODE>
__global__ __launch_bounds__(256, 4) void nc_conv_mfma(
    const unsigned short* __restrict__ xin, const unsigned short* __restrict__ Wf,
    const float* __restrict__ bias, void* __restrict__ yout) {
  constexpr int NCH = (CI * 9 + 31) / 32;
  __shared__ unsigned short xs[360 * 40];  // 28800 B
  int ij = blockIdx.x, qt = blockIdx.y, b = blockIdx.z;
  int i = ij >> 5, j = ij & 31;
  int tid = threadIdx.x;
  int lane = tid & 63, w = tid >> 6;
  int ncol = lane & 15, g4 = lane >> 4;

  // zero the l-halo columns once (bulk staging never writes cols 0 / 33)
  if (tid < 80) {
    int rr = tid >> 3;
    int e = tid & 7;
    int pos = rr * 36 + ((e >> 2) ? 33 : 0);
    half8 z = {};
    *(half8*)((char*)xs + pos * 80 + (e & 3) * 16) = z;
  }

  // per-q read base byte offset: pos_min = r*36 + l0 + ncol (tap (dk,dl) adds
  // ((dk+1)*36 + (dl+1))*80 bytes)
  int rbase[4];
#pragma unroll
  for (int q = 0; q < 4; ++q) {
    int n0 = (((w << 2) + q) << 4);
    int r = n0 >> 5, l0 = n0 & 31;
    rbase[q] = (r * 36 + l0 + ncol) * 80 + (g4 << 4);
  }

  floatx4 acc[4];
#pragma unroll
  for (int q = 0; q < 4; ++q) acc[q] = (floatx4){0.f, 0.f, 0.f, 0.f};

  for (int ch = 0; ch < NCH; ++ch) {
    __syncthreads();
    // ---- stage chunk ch: 1280 jobs = 16 kpairs x 10 rows x 8 colgroups ----
#pragma unroll
    for (int it = 0; it < 5; ++it) {
      int idx = tid + (it << 8);
      int colg = idx & 7;
      int kp = (idx >> 3) & 15;
      int row = idx >> 7;  // 0..9, wave-uniform
      int row_g = (qt << 3) - 1 + row;
      bool rv = (unsigned)row_g < 32u;
      const unsigned short* p0 = nullptr;
      const unsigned short* p1 = nullptr;
      int cip0 = (ch << 5) + (kp << 1);
      if (cip0 < CI * 9) {
        int ci = cip0 / 9, r9 = cip0 - ci * 9;
        int ii = i + r9 / 3 - 1, jj = j + r9 % 3 - 1;
        if ((unsigned)ii < 32u && (unsigned)jj < 32u)
          p0 = xin + ((size_t)(b * CI + ci) * 1024 + ii * 32 + jj) * 1024;
      }
      int cip1 = cip0 + 1;
      if (cip1 < CI * 9) {
        int ci = cip1 / 9, r9 = cip1 - ci * 9;
        int ii = i + r9 / 3 - 1, jj = j + r9 % 3 - 1;
        if ((unsigned)ii < 32u && (unsigned)jj < 32u)
          p1 = xin + ((size_t)(b * CI + ci) * 1024 + ii * 32 + jj) * 1024;
      }
      ushort4 a0 = {0, 0, 0, 0}, a1 = {0, 0, 0, 0};
      int goff = (row_g << 5) + (colg << 2);
      if (rv && p0) a0 = *(const ushort4*)(p0 + goff);
      if (rv && p1) a1 = *(const ushort4*)(p1 + goff);
      unsigned* dstw = (unsigned*)xs + (row * 36 + 1 + (colg << 2)) * 20 + kp;
      dstw[0]  = (unsigned)a0.x | ((unsigned)a1.x << 16);
      dstw[20] = (unsigned)a0.y | ((unsigned)a1.y << 16);
      dstw[40] = (unsigned)a0.z | ((unsigned)a1.z << 16);
      dstw[60] = (unsigned)a0.w | ((unsigned)a1.w << 16);
    }
    __syncthreads();

    // ---- 9 taps x 4 q-tiles of MFMA ----
    const unsigned short* wfp = Wf + (size_t)(ch * 9) * 512 + (lane << 3);
#pragma unroll
    for (int tap = 0; tap < 9; ++tap) {
      half8 af = *(const half8*)(wfp + tap * 512);
      const int off = ((tap / 3) * 36 + (tap % 3)) * 80;
#pragma unroll
      for (int q = 0; q < 4; ++q) {
        half8 bv = *(const half8*)((const char*)xs + rbase[q] + off);
        acc[q] = __builtin_amdgcn_mfma_f32_16x16x32_f16(af, bv, acc[q], 0, 0, 0);
      }
    }
  }

  // ---- epilogue ----
#pragma unroll
  for (int q = 0; q < 4; ++q) {
    int ng = (qt << 8) + (((w << 2) + q) << 4) + ncol;
    if (OUTMODE == 0) {
      unsigned short* t1 = (unsigned short*)yout;
#pragma unroll
      for (int r = 0; r < 4; ++r) {
        int co = (g4 << 2) + r;
        if (co < 10) {
          float vv = fmaxf(acc[q][r] + bias[co], 0.f);
          _Float16 hh = (_Float16)vv;
          t1[((size_t)(b * 10 + co) * 1024 + ij) * 1024 + ng] =
              __builtin_bit_cast(unsigned short, hh);
        }
      }
    } else {
      unsigned* t2p = (unsigned*)yout;
      int c0 = g4 << 2;
      float v0 = fmaxf(acc[q][0] + (c0 + 0 < 10 ? bias[c0 + 0] : 0.f), 0.f);
      float v1 = fmaxf(acc[q][1] + (c0 + 1 < 10 ? bias[c0 + 1] : 0.f), 0.f);
      float v2 = fmaxf(acc[q][2] + (c0 + 2 < 10 ? bias[c0 + 2] : 0.f), 0.f);
      float v3 = fmaxf(acc[q][3] + (c0 + 3 < 10 ? bias[c0 + 3] : 0.f), 0.f);
      int p0 = g4 << 1;
      if (p0 < 5)
        t2p[((size_t)(b * 5 + p0) * 1024 + ij) * 1024 + ng] = pack2(v0, v1);
      if (p0 + 1 < 5)
        t2p[((size_t)(b * 5 + p0 + 1) * 1024 + ij) * 1024 + ng] = pack2(v2, v3);
    }
  }
}

// ---------- conv3 (10 -> 1) via v_dot2 over ci-pairs ----------
template <bool ACCUM>
__global__ __launch_bounds__(256) void nc_conv3(
    const unsigned* __restrict__ t2p, const unsigned* __restrict__ w3p,
    const float* __restrict__ b3, float* __restrict__ yout) {
  __shared__ unsigned xs2[5][33 * 32];
  int ij = blockIdx.x, b = blockIdx.y;
  int i = ij >> 5, j = ij & 31;
  int tid = threadIdx.x;
  int k = tid >> 3, l4 = (tid & 7) << 2;
  float acc[4] = {0.f, 0.f, 0.f, 0.f};

  for (int di = -1; di <= 1; ++di) {
    int ii = i + di;
    for (int dj = -1; dj <= 1; ++dj) {
      int jj = j + dj;
      bool pv = ((unsigned)ii < 32u) && ((unsigned)jj < 32u);
      if (!pv) continue;  // block-uniform
      __syncthreads();
#pragma unroll
      for (int p = 0; p < 5; ++p) {
#pragma unroll
        for (int s = 0; s < 4; ++s) {
          int pos = (s << 8) + tid;
          unsigned v = t2p[((size_t)(b * 5 + p) * 1024 + ii * 32 + jj) * 1024 + pos];
          xs2[p][(pos >> 5) * 33 + (pos & 31)] = v;
        }
      }
      __syncthreads();
      int r9 = (di + 1) * 3 + (dj + 1);
#pragma unroll
      for (int p = 0; p < 5; ++p) {
        unsigned vv[3][6];
#pragma unroll
        for (int a = 0; a < 3; ++a)
#pragma unroll
          for (int bb2 = 0; bb2 < 6; ++bb2) {
            int rr = k + a - 1, cc = l4 + bb2 - 1;
            unsigned x = 0;
            if ((unsigned)rr < 32u && (unsigned)cc < 32u) x = xs2[p][rr * 33 + cc];
            vv[a][bb2] = x;
          }
#pragma unroll
        for (int a = 0; a < 3; ++a)
#pragma unroll
          for (int bc = 0; bc < 3; ++bc) {
            unsigned wp = w3p[p * 81 + r9 * 9 + a * 3 + bc];
#pragma unroll
            for (int r = 0; r < 4; ++r) acc[r] = dot2acc(vv[a][r + bc], wp, acc[r]);
          }
      }
    }
  }
  float bb = b3[0];
  size_t o = ((size_t)b * 1024 + ij) * 1024 + (k << 5) + l4;
  float4 out4;
  out4.x = fmaxf(acc[0] + bb, 0.f);
  out4.y = fmaxf(acc[1] + bb, 0.f);
  out4.z = fmaxf(acc[2] + bb, 0.f);
  out4.w = fmaxf(acc[3] + bb, 0.f);
  if (ACCUM) {
    float4 prev = *(const float4*)&yout[o];
    out4.x += prev.x; out4.y += prev.y; out4.z += prev.z; out4.w += prev.w;
  }
  *(float4*)&yout[o] = out4;
}

extern "C" void kernel_launch(void* const* d_in, const int* in_sizes, int n_in,
                              void* d_out, int out_size, void* d_ws, size_t ws_size,
                              hipStream_t stream) {
  const float* fA = (const float*)d_in[0];
  const float* fB = (const float*)d_in[1];
  const float* W1 = (const float*)d_in[2];
  const float* b1 = (const float*)d_in[3];
  const float* W2 = (const float*)d_in[4];
  const float* b2 = (const float*)d_in[5];
  const float* W3 = (const float*)d_in[6];
  const float* b3 = (const float*)d_in[7];
  float* out = (float*)d_out;

  char* ws = (char*)d_ws;
  const size_t SM = 16384;
  float* normA = (float*)(ws + 0 * SM);
  float* normB = (float*)(ws + 1 * SM);
  float* maxA1 = (float*)(ws + 2 * SM);
  float* maxA2 = (float*)(ws + 3 * SM);
  unsigned* maxBu1 = (unsigned*)(ws + 4 * SM);  // zeroed together with maxBu2
  unsigned* maxBu2 = (unsigned*)(ws + 5 * SM);
  char* p = ws + 6 * SM;
  float* corr = (float*)p;              p += (size_t)4 * 1024 * 1024 * 4;
  unsigned short* mm1h = (unsigned short*)p; p += (size_t)4 * 1024 * 1024 * 2;
  unsigned short* t1 = (unsigned short*)p;   p += (size_t)40 * 1024 * 1024 * 2;
  unsigned* t2p = (unsigned*)p;         p += (size_t)20 * 1024 * 1024 * 4;
  unsigned short* Wf = (unsigned short*)p;   p += 72 * 512 * 2;
  unsigned* w3p = (unsigned*)p;

  // front-end (fp32)
  nc_norms<<<32, 256, 0, stream>>>(fA, fB, normA, normB);
  nc_zero_u32<<<32, 256, 0, stream>>>(maxBu1, 8192);
  nc_wpack<<<73, 256, 0, stream>>>(W1, W2, W3, Wf, w3p);
  nc_gemm<<<dim3(16, 16, 4), 256, 0, stream>>>(fA, fB, normA, normB, corr);
  nc_rowmax<<<4096, 256, 0, stream>>>(corr, maxA1);
  nc_colmax<<<dim3(4, 64, 4), 256, 0, stream>>>(corr, maxBu1);
  nc_mm_f16<<<4096, 256, 0, stream>>>(corr, maxA1, maxBu1, mm1h);

  dim3 cg(1024, 4, 4);  // (ij, quarter, b)
  dim3 c3(1024, 4);
  // branch A (normal weights)
  nc_conv_mfma<1, 0><<<cg, 256, 0, stream>>>(mm1h, Wf + 0 * 512, b1, t1);
  nc_conv_mfma<10, 1><<<cg, 256, 0, stream>>>(t1, Wf + 18 * 512, b2, t2p);
  nc_conv3<false><<<c3, 256, 0, stream>>>(t2p, w3p + 0, b3, out);
  // branch B (axis-swapped weights == P . nc . P)
  nc_conv_mfma<1, 0><<<cg, 256, 0, stream>>>(mm1h, Wf + 9 * 512, b1, t1);
  nc_conv_mfma<10, 1><<<cg, 256, 0, stream>>>(t1, Wf + 45 * 512, b2, t2p);
  nc_conv3<true><<<c3, 256, 0, stream>>>(t2p, w3p + 405, b3, out);

  // final mutual matching (fp32, in place on d_out)
  nc_rowmax<<<4096, 256, 0, stream>>>(out, maxA2);
  nc_colmax<<<dim3(4, 64, 4), 256, 0, stream>>>(out, maxBu2);
  nc_mm_f32<<<4096, 256, 0, stream>>>(out, maxA2, maxBu2, out);
}

// Round 5
// 1213.589 us; speedup vs baseline: 2.7056x; 1.0150x over previous
//
#include <hip/hip_runtime.h>
#include <math.h>

typedef _Float16 half8 __attribute__((ext_vector_type(8)));
typedef _Float16 half2t __attribute__((ext_vector_type(2)));
typedef float floatx4 __attribute__((ext_vector_type(4)));

static __device__ __forceinline__ unsigned f2o(float f) {
  unsigned b = __float_as_uint(f);
  return (b & 0x80000000u) ? ~b : (b | 0x80000000u);
}
static __device__ __forceinline__ float o2f(unsigned u) {
  return __uint_as_float((u & 0x80000000u) ? (u & 0x7fffffffu) : ~u);
}
static __device__ __forceinline__ unsigned pack2(float a, float b) {
  _Float16 ha = (_Float16)a, hb = (_Float16)b;
  unsigned short ua = __builtin_bit_cast(unsigned short, ha);
  unsigned short ub = __builtin_bit_cast(unsigned short, hb);
  return (unsigned)ua | ((unsigned)ub << 16);
}
static __device__ __forceinline__ float dot2acc(unsigned x, unsigned w, float acc) {
  half2t xh = __builtin_bit_cast(half2t, x);
  half2t wh = __builtin_bit_cast(half2t, w);
#if __has_builtin(__builtin_amdgcn_fdot2)
  return __builtin_amdgcn_fdot2(xh, wh, acc, false);
#else
  return fmaf((float)xh[0], (float)wh[0], fmaf((float)xh[1], (float)wh[1], acc));
#endif
}

__global__ void nc_zero_u32(unsigned* __restrict__ p, int n) {
  int i = blockIdx.x * blockDim.x + threadIdx.x;
  if (i < n) p[i] = 0u;
}

// ---------- L2 norms (fp32) ----------
__global__ __launch_bounds__(256) void nc_norms(const float* __restrict__ fA,
                                                const float* __restrict__ fB,
                                                float* __restrict__ nA,
                                                float* __restrict__ nB) {
  int idx = blockIdx.x * blockDim.x + threadIdx.x;
  const float* f = (idx & 4096) ? fB : fA;
  float* out = (idx & 4096) ? nB : nA;
  int bp = idx & 4095;
  const float* base = f + ((size_t)(bp >> 10) << 20) + (bp & 1023);
  float s = 0.f;
#pragma unroll 8
  for (int c = 0; c < 1024; ++c) {
    float v = base[(size_t)c << 10];
    s = fmaf(v, v, s);
  }
  out[bp] = sqrtf(s + 1e-6f);
}

// ---------- correlation GEMM (fp32) ----------
__global__ __launch_bounds__(256) void nc_gemm(const float* __restrict__ A,
                                               const float* __restrict__ B,
                                               const float* __restrict__ nA,
                                               const float* __restrict__ nB,
                                               float* __restrict__ C) {
  __shared__ float As[16][64];
  __shared__ float Bs[16][64];
  int b = blockIdx.z;
  int p0 = blockIdx.y << 6, q0 = blockIdx.x << 6;
  const float* Ab = A + ((size_t)b << 20);
  const float* Bb = B + ((size_t)b << 20);
  int tid = threadIdx.x;
  int tx = tid & 15, ty = tid >> 4;
  int lm = tid & 63, lk4 = (tid >> 6) << 2;
  float acc[4][4] = {};
  for (int k0 = 0; k0 < 1024; k0 += 16) {
    __syncthreads();
#pragma unroll
    for (int t = 0; t < 4; ++t) {
      int kk = lk4 + t;
      As[kk][lm] = Ab[((size_t)(k0 + kk) << 10) + p0 + lm];
      Bs[kk][lm] = Bb[((size_t)(k0 + kk) << 10) + q0 + lm];
    }
    __syncthreads();
#pragma unroll
    for (int kk = 0; kk < 16; ++kk) {
      const float4 av = *(const float4*)&As[kk][ty << 2];
      const float4 bv = *(const float4*)&Bs[kk][tx << 2];
      float a4[4] = {av.x, av.y, av.z, av.w};
      float b4[4] = {bv.x, bv.y, bv.z, bv.w};
#pragma unroll
      for (int r = 0; r < 4; ++r)
#pragma unroll
        for (int c = 0; c < 4; ++c) acc[r][c] = fmaf(a4[r], b4[c], acc[r][c]);
    }
  }
  float rn[4], cn[4];
#pragma unroll
  for (int r = 0; r < 4; ++r) rn[r] = nA[(b << 10) + p0 + (ty << 2) + r];
#pragma unroll
  for (int c = 0; c < 4; ++c) cn[c] = nB[(b << 10) + q0 + (tx << 2) + c];
#pragma unroll
  for (int r = 0; r < 4; ++r) {
    float4 o;
    o.x = acc[r][0] / (rn[r] * cn[0]);
    o.y = acc[r][1] / (rn[r] * cn[1]);
    o.z = acc[r][2] / (rn[r] * cn[2]);
    o.w = acc[r][3] / (rn[r] * cn[3]);
    *(float4*)&C[((size_t)b << 20) + ((size_t)(p0 + (ty << 2) + r) << 10) + q0 + (tx << 2)] = o;
  }
}

// ---------- row / col max (fp32) ----------
__global__ __launch_bounds__(256) void nc_rowmax(const float* __restrict__ X,
                                                 float* __restrict__ rmax) {
  int row = blockIdx.x;
  const float* x = X + ((size_t)row << 10);
  int tid = threadIdx.x;
  float m = fmaxf(fmaxf(x[tid], x[tid + 256]), fmaxf(x[tid + 512], x[tid + 768]));
  __shared__ float red[256];
  red[tid] = m;
  __syncthreads();
  for (int s = 128; s > 0; s >>= 1) {
    if (tid < s) red[tid] = fmaxf(red[tid], red[tid + s]);
    __syncthreads();
  }
  if (tid == 0) rmax[row] = red[0];
}

__global__ __launch_bounds__(256) void nc_colmax(const float* __restrict__ X,
                                                 unsigned* __restrict__ cmaxu) {
  int b = blockIdx.z;
  int q = (blockIdx.x << 8) + threadIdx.x;
  int p0 = blockIdx.y << 4;
  const float* x = X + ((size_t)b << 20) + ((size_t)p0 << 10) + q;
  float m = -INFINITY;
#pragma unroll
  for (int r = 0; r < 16; ++r) m = fmaxf(m, x[(size_t)r << 10]);
  atomicMax(&cmaxu[(b << 10) + q], f2o(m));
}

// ---------- mutual matching ----------
__global__ __launch_bounds__(256) void nc_mm_f32(const float* __restrict__ X,
                                                 const float* __restrict__ rmax,
                                                 const unsigned* __restrict__ cmaxu,
                                                 float* __restrict__ Y) {
  size_t i4 = (size_t)blockIdx.x * 256 + threadIdx.x;
  size_t base = i4 << 2;
  float4 x = *(const float4*)&X[base];
  float ma = rmax[base >> 10] + 1e-5f;
  const unsigned* cm = &cmaxu[((base >> 20) << 10) + (base & 1023)];
  float4 y;
  y.x = x.x * x.x * x.x / (ma * (o2f(cm[0]) + 1e-5f));
  y.y = x.y * x.y * x.y / (ma * (o2f(cm[1]) + 1e-5f));
  y.z = x.z * x.z * x.z / (ma * (o2f(cm[2]) + 1e-5f));
  y.w = x.w * x.w * x.w / (ma * (o2f(cm[3]) + 1e-5f));
  *(float4*)&Y[base] = y;
}

__global__ __launch_bounds__(256) void nc_mm_f16(const float* __restrict__ X,
                                                 const float* __restrict__ rmax,
                                                 const unsigned* __restrict__ cmaxu,
                                                 unsigned short* __restrict__ Y16) {
  size_t i4 = (size_t)blockIdx.x * 256 + threadIdx.x;
  size_t base = i4 << 2;
  float4 x = *(const float4*)&X[base];
  float ma = rmax[base >> 10] + 1e-5f;
  const unsigned* cm = &cmaxu[((base >> 20) << 10) + (base & 1023)];
  float y0 = x.x * x.x * x.x / (ma * (o2f(cm[0]) + 1e-5f));
  float y1 = x.y * x.y * x.y / (ma * (o2f(cm[1]) + 1e-5f));
  float y2 = x.z * x.z * x.z / (ma * (o2f(cm[2]) + 1e-5f));
  float y3 = x.w * x.w * x.w / (ma * (o2f(cm[3]) + 1e-5f));
  unsigned* dst = (unsigned*)&Y16[base];
  dst[0] = pack2(y0, y1);
  dst[1] = pack2(y2, y3);
}

// ---------- weight prepack (unchanged layout) ----------
__global__ void nc_wpack(const float* __restrict__ W1, const float* __restrict__ W2,
                         const float* __restrict__ W3,
                         unsigned short* __restrict__ Wf, unsigned* __restrict__ w3p) {
  int f = blockIdx.x;
  int t = threadIdx.x;
  if (f < 72) {
    int v, chunk, tap, CI;
    const float* W;
    if (f < 18) { v = f / 9; tap = f % 9; chunk = 0; CI = 1; W = W1; }
    else { int g = f - 18; v = g / 27; g %= 27; chunk = g / 9; tap = g % 9; CI = 10; W = W2; }
    for (int e = t; e < 512; e += 256) {
      int lane = e >> 3, j = e & 7;
      int co = lane & 15;
      int k = ((lane >> 4) << 3) + j;
      int cip = chunk * 32 + k;
      float val = 0.f;
      if (co < 10 && cip < CI * 9) {
        int ci = cip / 9, r = cip % 9;
        int widx = v ? (tap * 9 + r) : (r * 9 + tap);
        val = W[(co * CI + ci) * 81 + widx];
      }
      _Float16 h = (_Float16)val;
      Wf[f * 512 + e] = __builtin_bit_cast(unsigned short, h);
    }
  } else {
    for (int e = t; e < 2 * 5 * 81; e += 256) {
      int v = e / 405;
      int rem = e - v * 405;
      int p = rem / 81;
      int t81 = rem - p * 81;
      int r = t81 / 9, ab = t81 - r * 9;
      int widx = v ? (ab * 9 + r) : (r * 9 + ab);
      w3p[e] = pack2(W3[(2 * p) * 81 + widx], W3[(2 * p + 1) * 81 + widx]);
    }
  }
}

// ---------- MFMA 4D conv body (quarter-plane blocks) ----------
// Block = (ij-swizzled, quarter, b): 8 output k-rows (256 pos), all CO.
// LDS: xs[pos][kslot], pos = row*36 + 1 + l, kslot stride 40 halves (80 B =
// 5x16B -> b128 read 16B-groups coprime with 8). Staging lane map kp-fast:
// write bank = C + kp + 16*(colg&1), kp 0..15 -> all 32 banks, 2-way (free).
// XCD swizzle: ij = (bx&7)*128 + (bx>>3) gives each XCD a contiguous ij band.
template <int CI, int OUTMODE>
static __device__ __forceinline__ void nc_conv_body(
    const unsigned short* __restrict__ xin, const unsigned short* __restrict__ Wf,
    const float* __restrict__ bias, void* __restrict__ yout) {
  constexpr int NCH = (CI * 9 + 31) / 32;
  __shared__ unsigned short xs[360 * 40];  // 28800 B
  int bx = blockIdx.x, qt = blockIdx.y, b = blockIdx.z;
  int ij = ((bx & 7) << 7) + (bx >> 3);  // XCD-contiguous ij bands
  int i = ij >> 5, j = ij & 31;
  int tid = threadIdx.x;
  int lane = tid & 63, w = tid >> 6;
  int ncol = lane & 15, g4 = lane >> 4;

  // zero the l-halo columns once (bulk staging never writes cols 0 / 33)
  if (tid < 80) {
    int rr = tid >> 3;
    int e = tid & 7;
    int pos = rr * 36 + ((e >> 2) ? 33 : 0);
    half8 z = {};
    *(half8*)((char*)xs + pos * 80 + (e & 3) * 16) = z;
  }

  // per-q read base byte offset (tap (dk,dl) adds ((dk+1)*36+(dl+1))*80 bytes)
  int rbase[4];
#pragma unroll
  for (int q = 0; q < 4; ++q) {
    int n0 = (((w << 2) + q) << 4);
    int r = n0 >> 5, l0 = n0 & 31;
    rbase[q] = (r * 36 + l0 + ncol) * 80 + (g4 << 4);
  }

  floatx4 acc[4];
#pragma unroll
  for (int q = 0; q < 4; ++q) acc[q] = (floatx4){0.f, 0.f, 0.f, 0.f};

  for (int ch = 0; ch < NCH; ++ch) {
    __syncthreads();
    // ---- stage chunk ch: 1280 jobs = 16 kp x 8 colg x 10 rows (kp-fast) ----
#pragma unroll
    for (int it = 0; it < 5; ++it) {
      int idx = tid + (it << 8);
      int kp = idx & 15;
      int colg = (idx >> 4) & 7;
      int row = idx >> 7;  // 0..9, wave-uniform
      int row_g = (qt << 3) - 1 + row;
      bool rv = (unsigned)row_g < 32u;
      const unsigned short* p0 = nullptr;
      const unsigned short* p1 = nullptr;
      int cip0 = (ch << 5) + (kp << 1);
      if (cip0 < CI * 9) {
        int ci = cip0 / 9, r9 = cip0 - ci * 9;
        int ii = i + r9 / 3 - 1, jj = j + r9 % 3 - 1;
        if ((unsigned)ii < 32u && (unsigned)jj < 32u)
          p0 = xin + ((size_t)(b * CI + ci) * 1024 + ii * 32 + jj) * 1024;
      }
      int cip1 = cip0 + 1;
      if (cip1 < CI * 9) {
        int ci = cip1 / 9, r9 = cip1 - ci * 9;
        int ii = i + r9 / 3 - 1, jj = j + r9 % 3 - 1;
        if ((unsigned)ii < 32u && (unsigned)jj < 32u)
          p1 = xin + ((size_t)(b * CI + ci) * 1024 + ii * 32 + jj) * 1024;
      }
      ushort4 a0 = {0, 0, 0, 0}, a1 = {0, 0, 0, 0};
      int goff = (row_g << 5) + (colg << 2);
      if (rv && p0) a0 = *(const ushort4*)(p0 + goff);
      if (rv && p1) a1 = *(const ushort4*)(p1 + goff);
      unsigned* dstw = (unsigned*)xs + (row * 36 + 1 + (colg << 2)) * 20 + kp;
      dstw[0]  = (unsigned)a0.x | ((unsigned)a1.x << 16);
      dstw[20] = (unsigned)a0.y | ((unsigned)a1.y << 16);
      dstw[40] = (unsigned)a0.z | ((unsigned)a1.z << 16);
      dstw[60] = (unsigned)a0.w | ((unsigned)a1.w << 16);
    }
    __syncthreads();

    // ---- 9 taps x 4 q-tiles of MFMA ----
    const unsigned short* wfp = Wf + (size_t)(ch * 9) * 512 + (lane << 3);
#pragma unroll
    for (int tap = 0; tap < 9; ++tap) {
      half8 af = *(const half8*)(wfp + tap * 512);
      const int off = ((tap / 3) * 36 + (tap % 3)) * 80;
#pragma unroll
      for (int q = 0; q < 4; ++q) {
        half8 bv = *(const half8*)((const char*)xs + rbase[q] + off);
        acc[q] = __builtin_amdgcn_mfma_f32_16x16x32_f16(af, bv, acc[q], 0, 0, 0);
      }
    }
  }

  // ---- epilogue ----
#pragma unroll
  for (int q = 0; q < 4; ++q) {
    int ng = (qt << 8) + (((w << 2) + q) << 4) + ncol;
    if (OUTMODE == 0) {
      unsigned short* t1 = (unsigned short*)yout;
#pragma unroll
      for (int r = 0; r < 4; ++r) {
        int co = (g4 << 2) + r;
        if (co < 10) {
          float vv = fmaxf(acc[q][r] + bias[co], 0.f);
          _Float16 hh = (_Float16)vv;
          t1[((size_t)(b * 10 + co) * 1024 + ij) * 1024 + ng] =
              __builtin_bit_cast(unsigned short, hh);
        }
      }
    } else {
      unsigned* t2p = (unsigned*)yout;
      int c0 = g4 << 2;
      float v0 = fmaxf(acc[q][0] + (c0 + 0 < 10 ? bias[c0 + 0] : 0.f), 0.f);
      float v1 = fmaxf(acc[q][1] + (c0 + 1 < 10 ? bias[c0 + 1] : 0.f), 0.f);
      float v2 = fmaxf(acc[q][2] + (c0 + 2 < 10 ? bias[c0 + 2] : 0.f), 0.f);
      float v3 = fmaxf(acc[q][3] + (c0 + 3 < 10 ? bias[c0 + 3] : 0.f), 0.f);
      int p0 = g4 << 1;
      if (p0 < 5)
        t2p[((size_t)(b * 5 + p0) * 1024 + ij) * 1024 + ng] = pack2(v0, v1);
      if (p0 + 1 < 5)
        t2p[((size_t)(b * 5 + p0 + 1) * 1024 + ij) * 1024 + ng] = pack2(v2, v3);
    }
  }
}

__global__ __launch_bounds__(256, 5) void nc_conv1_k(
    const unsigned short* __restrict__ xin, const unsigned short* __restrict__ Wf,
    const float* __restrict__ bias, void* __restrict__ yout) {
  nc_conv_body<1, 0>(xin, Wf, bias, yout);
}
__global__ __launch_bounds__(256, 5) void nc_conv2_k(
    const unsigned short* __restrict__ xin, const unsigned short* __restrict__ Wf,
    const float* __restrict__ bias, void* __restrict__ yout) {
  nc_conv_body<10, 1>(xin, Wf, bias, yout);
}

// ---------- conv3 (10 -> 1) via v_dot2 over ci-pairs ----------
template <bool ACCUM>
__global__ __launch_bounds__(256) void nc_conv3(
    const unsigned* __restrict__ t2p, const unsigned* __restrict__ w3p,
    const float* __restrict__ b3, float* __restrict__ yout) {
  __shared__ unsigned xs2[5][33 * 32];
  int bx = blockIdx.x, b = blockIdx.y;
  int ij = ((bx & 7) << 7) + (bx >> 3);
  int i = ij >> 5, j = ij & 31;
  int tid = threadIdx.x;
  int k = tid >> 3, l4 = (tid & 7) << 2;
  float acc[4] = {0.f, 0.f, 0.f, 0.f};

  for (int di = -1; di <= 1; ++di) {
    int ii = i + di;
    for (int dj = -1; dj <= 1; ++dj) {
      int jj = j + dj;
      bool pv = ((unsigned)ii < 32u) && ((unsigned)jj < 32u);
      if (!pv) continue;  // block-uniform
      __syncthreads();
#pragma unroll
      for (int p = 0; p < 5; ++p) {
#pragma unroll
        for (int s = 0; s < 4; ++s) {
          int pos = (s << 8) + tid;
          unsigned v = t2p[((size_t)(b * 5 + p) * 1024 + ii * 32 + jj) * 1024 + pos];
          xs2[p][(pos >> 5) * 33 + (pos & 31)] = v;
        }
      }
      __syncthreads();
      int r9 = (di + 1) * 3 + (dj + 1);
#pragma unroll
      for (int p = 0; p < 5; ++p) {
        unsigned vv[3][6];
#pragma unroll
        for (int a = 0; a < 3; ++a)
#pragma unroll
          for (int bb2 = 0; bb2 < 6; ++bb2) {
            int rr = k + a - 1, cc = l4 + bb2 - 1;
            unsigned x = 0;
            if ((unsigned)rr < 32u && (unsigned)cc < 32u) x = xs2[p][rr * 33 + cc];
            vv[a][bb2] = x;
          }
#pragma unroll
        for (int a = 0; a < 3; ++a)
#pragma unroll
          for (int bc = 0; bc < 3; ++bc) {
            unsigned wp = w3p[p * 81 + r9 * 9 + a * 3 + bc];
#pragma unroll
            for (int r = 0; r < 4; ++r) acc[r] = dot2acc(vv[a][r + bc], wp, acc[r]);
          }
      }
    }
  }
  float bb = b3[0];
  size_t o = ((size_t)b * 1024 + ij) * 1024 + (k << 5) + l4;
  float4 out4;
  out4.x = fmaxf(acc[0] + bb, 0.f);
  out4.y = fmaxf(acc[1] + bb, 0.f);
  out4.z = fmaxf(acc[2] + bb, 0.f);
  out4.w = fmaxf(acc[3] + bb, 0.f);
  if (ACCUM) {
    float4 prev = *(const float4*)&yout[o];
    out4.x += prev.x; out4.y += prev.y; out4.z += prev.z; out4.w += prev.w;
  }
  *(float4*)&yout[o] = out4;
}

extern "C" void kernel_launch(void* const* d_in, const int* in_sizes, int n_in,
                              void* d_out, int out_size, void* d_ws, size_t ws_size,
                              hipStream_t stream) {
  const float* fA = (const float*)d_in[0];
  const float* fB = (const float*)d_in[1];
  const float* W1 = (const float*)d_in[2];
  const float* b1 = (const float*)d_in[3];
  const float* W2 = (const float*)d_in[4];
  const float* b2 = (const float*)d_in[5];
  const float* W3 = (const float*)d_in[6];
  const float* b3 = (const float*)d_in[7];
  float* out = (float*)d_out;

  char* ws = (char*)d_ws;
  const size_t SM = 16384;
  float* normA = (float*)(ws + 0 * SM);
  float* normB = (float*)(ws + 1 * SM);
  float* maxA1 = (float*)(ws + 2 * SM);
  float* maxA2 = (float*)(ws + 3 * SM);
  unsigned* maxBu1 = (unsigned*)(ws + 4 * SM);  // zeroed together with maxBu2
  unsigned* maxBu2 = (unsigned*)(ws + 5 * SM);
  char* p = ws + 6 * SM;
  float* corr = (float*)p;              p += (size_t)4 * 1024 * 1024 * 4;
  unsigned short* mm1h = (unsigned short*)p; p += (size_t)4 * 1024 * 1024 * 2;
  unsigned short* t1 = (unsigned short*)p;   p += (size_t)40 * 1024 * 1024 * 2;
  unsigned* t2p = (unsigned*)p;         p += (size_t)20 * 1024 * 1024 * 4;
  unsigned short* Wf = (unsigned short*)p;   p += 72 * 512 * 2;
  unsigned* w3p = (unsigned*)p;

  // front-end (fp32)
  nc_norms<<<32, 256, 0, stream>>>(fA, fB, normA, normB);
  nc_zero_u32<<<32, 256, 0, stream>>>(maxBu1, 8192);
  nc_wpack<<<73, 256, 0, stream>>>(W1, W2, W3, Wf, w3p);
  nc_gemm<<<dim3(16, 16, 4), 256, 0, stream>>>(fA, fB, normA, normB, corr);
  nc_rowmax<<<4096, 256, 0, stream>>>(corr, maxA1);
  nc_colmax<<<dim3(4, 64, 4), 256, 0, stream>>>(corr, maxBu1);
  nc_mm_f16<<<4096, 256, 0, stream>>>(corr, maxA1, maxBu1, mm1h);

  dim3 cg(1024, 4, 4);  // (ij, quarter, b)
  dim3 c3(1024, 4);
  // branch A (normal weights)
  nc_conv1_k<<<cg, 256, 0, stream>>>(mm1h, Wf + 0 * 512, b1, t1);
  nc_conv2_k<<<cg, 256, 0, stream>>>(t1, Wf + 18 * 512, b2, t2p);
  nc_conv3<false><<<c3, 256, 0, stream>>>(t2p, w3p + 0, b3, out);
  // branch B (axis-swapped weights == P . nc . P)
  nc_conv1_k<<<cg, 256, 0, stream>>>(mm1h, Wf + 9 * 512, b1, t1);
  nc_conv2_k<<<cg, 256, 0, stream>>>(t1, Wf + 45 * 512, b2, t2p);
  nc_conv3<true><<<c3, 256, 0, stream>>>(t2p, w3p + 405, b3, out);

  // final mutual matching (fp32, in place on d_out)
  nc_rowmax<<<4096, 256, 0, stream>>>(out, maxA2);
  nc_colmax<<<dim3(4, 64, 4), 256, 0, stream>>>(out, maxBu2);
  nc_mm_f32<<<4096, 256, 0, stream>>>(out, maxA2, maxBu2, out);
}